// Round 2
// baseline (1095.856 us; speedup 1.0000x reference)
//
#include <hip/hip_runtime.h>

#define N_NODES 50000
#define N_EDGES 800000
#define F_IN    128
#define HID     32
#define HEADS   4
#define OUT_C   16

// ---------------------------------------------------------------- GEMM: h0 = x @ Wemb + bemb
__global__ __launch_bounds__(256) void k_emb(const float* __restrict__ x,
                                             const float* __restrict__ Wemb,
                                             const float* __restrict__ bemb,
                                             float* __restrict__ h0) {
    __shared__ float Wl[F_IN][HID];     // 16 KB
    __shared__ float xs[8][F_IN + 1];   // pad +1: avoid bank conflicts on xs[ln][k]
    __shared__ float bl[HID];
    int t = threadIdx.x;
    for (int i = t; i < F_IN * HID; i += 256) Wl[i / HID][i % HID] = Wemb[i];
    if (t < HID) bl[t] = bemb[t];
    int node0 = blockIdx.x * 8;
    for (int i = t; i < 8 * F_IN; i += 256) {
        int ln = i / F_IN, k = i % F_IN;
        xs[ln][k] = x[(node0 + ln) * F_IN + k];
    }
    __syncthreads();
    int ln = t >> 5, col = t & 31;
    float acc = bl[col];
    #pragma unroll
    for (int k = 0; k < F_IN; k++) acc += xs[ln][k] * Wl[k][col];
    h0[(node0 + ln) * HID + col] = acc;
}

// ---------------------------------------------------------------- GEMM: h1 = h0 @ W1   [N,32]x[32,128]
__global__ __launch_bounds__(256) void k_h1(const float* __restrict__ h0,
                                            const float* __restrict__ W1,
                                            float* __restrict__ h1) {
    __shared__ float Wl[HID][HEADS * HID];  // 32x128 fp32 = 16 KB
    __shared__ float xs[2][HID];
    int t = threadIdx.x;
    for (int i = t; i < HID * 128; i += 256) Wl[i / 128][i % 128] = W1[i];
    int node0 = blockIdx.x * 2;
    for (int i = t; i < 2 * HID; i += 256) {
        int ln = i / HID, k = i % HID;
        xs[ln][k] = h0[(node0 + ln) * HID + k];
    }
    __syncthreads();
    int ln = t >> 7, col = t & 127;
    float acc = 0.f;
    #pragma unroll
    for (int k = 0; k < HID; k++) acc += xs[ln][k] * Wl[k][col];
    h1[(node0 + ln) * 128 + col] = acc;
}

// ---------------------------------------------------------------- GEMM: h2 = out1 @ W2   [N,128]x[128,64]
__global__ __launch_bounds__(256) void k_h2(const float* __restrict__ hin,
                                            const float* __restrict__ W2,
                                            float* __restrict__ h2) {
    __shared__ float Wl[128][64];       // 32 KB
    __shared__ float xs[4][129];
    int t = threadIdx.x;
    for (int i = t; i < 128 * 64; i += 256) Wl[i / 64][i % 64] = W2[i];
    int node0 = blockIdx.x * 4;
    for (int i = t; i < 4 * 128; i += 256) {
        int ln = i >> 7, k = i & 127;
        xs[ln][k] = hin[(node0 + ln) * 128 + k];
    }
    __syncthreads();
    int ln = t >> 6, col = t & 63;
    float acc = 0.f;
    #pragma unroll
    for (int k = 0; k < 128; k++) acc += xs[ln][k] * Wl[k][col];
    h2[(node0 + ln) * 64 + col] = acc;
}

// ---------------------------------------------------------------- alpha_src/alpha_dst: [N,H] dots over C
template <int C>
__global__ __launch_bounds__(256) void k_alpha(const float* __restrict__ h,
                                               const float* __restrict__ a_src,
                                               const float* __restrict__ a_dst,
                                               float* __restrict__ as, float* __restrict__ ad) {
    int t = blockIdx.x * 256 + threadIdx.x;
    if (t >= N_NODES * HEADS) return;
    int hh = t & (HEADS - 1);
    const float* hp = h + t * C;   // t = n*HEADS + hh, h layout [N, HEADS*C]
    float s0 = 0.f, s1 = 0.f;
    #pragma unroll
    for (int c = 0; c < C; c++) {
        float v = hp[c];
        s0 += v * a_src[hh * C + c];
        s1 += v * a_dst[hh * C + c];
    }
    as[t] = s0;
    ad[t] = s1;
}

// ---------------------------------------------------------------- CSR build
__global__ __launch_bounds__(256) void k_count(const int* __restrict__ ei, int* __restrict__ counts) {
    int e = blockIdx.x * 256 + threadIdx.x;
    if (e >= N_EDGES) return;
    atomicAdd(&counts[ei[N_EDGES + e]], 1);
}

__global__ __launch_bounds__(1024) void k_scan(const int* __restrict__ counts, int* __restrict__ rowptr) {
    __shared__ int buf[1024];
    __shared__ int carry;
    int t = threadIdx.x;
    if (t == 0) carry = 0;
    __syncthreads();
    for (int base = 0; base < N_NODES; base += 1024) {
        int i = base + t;
        int v = (i < N_NODES) ? counts[i] : 0;
        buf[t] = v;
        __syncthreads();
        for (int off = 1; off < 1024; off <<= 1) {
            int add = (t >= off) ? buf[t - off] : 0;
            __syncthreads();
            buf[t] += add;
            __syncthreads();
        }
        int incl = buf[t];
        int c = carry;
        if (i < N_NODES) rowptr[i] = c + incl - v;   // exclusive scan
        __syncthreads();
        if (t == 1023) carry = c + incl;
        __syncthreads();
    }
    if (t == 0) rowptr[N_NODES] = carry;
}

__global__ __launch_bounds__(256) void k_fill(const int* __restrict__ ei, int* __restrict__ cursor,
                                              int* __restrict__ eidx) {
    int e = blockIdx.x * 256 + threadIdx.x;
    if (e >= N_EDGES) return;
    int d = ei[N_EDGES + e];
    int pos = atomicAdd(&cursor[d], 1);
    eidx[pos] = e;
}

// ---------------------------------------------------------------- per-edge exp(leaky_relu) + denom atomics
__global__ __launch_bounds__(256) void k_edge_sum(const int* __restrict__ ei,
                                                  const float* __restrict__ as,
                                                  const float* __restrict__ ad,
                                                  float* __restrict__ ew, float* __restrict__ ssum) {
    int e = blockIdx.x * 256 + threadIdx.x;
    if (e >= N_EDGES) return;
    int s = ei[e], d = ei[N_EDGES + e];
    float4 av = *(const float4*)(as + s * 4);
    float4 dv = *(const float4*)(ad + d * 4);
    float w[4];
    float vs[4] = {av.x + dv.x, av.y + dv.y, av.z + dv.z, av.w + dv.w};
    #pragma unroll
    for (int h = 0; h < 4; h++) {
        float v = vs[h];
        v = (v > 0.f) ? v : 0.2f * v;       // leaky_relu(0.2)
        w[h] = __expf(v);                   // softmax shift-invariant; logits are O(1)
    }
    *(float4*)(ew + e * 4) = make_float4(w[0], w[1], w[2], w[3]);
    #pragma unroll
    for (int h = 0; h < 4; h++) atomicAdd(&ssum[d * 4 + h], w[h]);
}

// ---------------------------------------------------------------- layer-1 gather: out1 = elu(seg_sum + b1)
__global__ __launch_bounds__(256) void k_gather1(const int* __restrict__ ei,
                                                 const int* __restrict__ rowptr,
                                                 const int* __restrict__ eidx,
                                                 const float* __restrict__ h1,
                                                 const float* __restrict__ ew,
                                                 const float* __restrict__ ssum,
                                                 const float* __restrict__ b1,
                                                 float* __restrict__ out1) {
    int t = threadIdx.x;
    int node = blockIdx.x * 2 + (t >> 7);
    int j = t & 127;
    int head = j >> 5;
    int beg = rowptr[node], end = rowptr[node + 1];
    float rs = 1.0f / (ssum[node * 4 + head] + 1e-16f);
    float acc = 0.f;
    for (int k = beg; k < end; k++) {
        int e = eidx[k];
        int src = ei[e];
        float alpha = ew[e * 4 + head] * rs;
        acc += h1[src * 128 + j] * alpha;
    }
    float v = acc + b1[j];
    out1[node * 128 + j] = (v > 0.f) ? v : (__expf(v) - 1.0f);   // ELU
}

// ---------------------------------------------------------------- layer-2 gather + head-mean + b2 + log_softmax
__global__ __launch_bounds__(256) void k_gather2(const int* __restrict__ ei,
                                                 const int* __restrict__ rowptr,
                                                 const int* __restrict__ eidx,
                                                 const float* __restrict__ h2,
                                                 const float* __restrict__ ew,
                                                 const float* __restrict__ ssum,
                                                 const float* __restrict__ b2,
                                                 float* __restrict__ out) {
    int t = threadIdx.x;
    int node = blockIdx.x * 4 + (t >> 6);
    int j = t & 63;
    int head = j >> 4, c = j & 15;
    int beg = rowptr[node], end = rowptr[node + 1];
    float rs = 1.0f / (ssum[node * 4 + head] + 1e-16f);
    float acc = 0.f;
    for (int k = beg; k < end; k++) {
        int e = eidx[k];
        int src = ei[e];
        acc += h2[src * 64 + j] * (ew[e * 4 + head] * rs);
    }
    // mean over 4 heads (lanes j, j^16, j^32 hold same c, different head)
    acc += __shfl_xor(acc, 16, 64);
    acc += __shfl_xor(acc, 32, 64);
    float v = acc * 0.25f + b2[c];
    // log_softmax over the 16 classes (within each 16-lane group)
    float m = v;
    #pragma unroll
    for (int mask = 1; mask < 16; mask <<= 1) m = fmaxf(m, __shfl_xor(m, mask, 64));
    float ex = __expf(v - m);
    float se = ex;
    #pragma unroll
    for (int mask = 1; mask < 16; mask <<= 1) se += __shfl_xor(se, mask, 64);
    float res = (v - m) - __logf(se);
    if (j < 16) out[node * 16 + c] = res;
}

// ================================================================ host
extern "C" void kernel_launch(void* const* d_in, const int* in_sizes, int n_in,
                              void* d_out, int out_size, void* d_ws, size_t ws_size,
                              hipStream_t stream) {
    const float* x      = (const float*)d_in[0];
    const int*   ei     = (const int*)d_in[1];
    const float* Wemb   = (const float*)d_in[2];
    const float* bemb   = (const float*)d_in[3];
    const float* W1     = (const float*)d_in[4];
    const float* a_src1 = (const float*)d_in[5];
    const float* a_dst1 = (const float*)d_in[6];
    const float* b1     = (const float*)d_in[7];
    const float* W2     = (const float*)d_in[8];
    const float* a_src2 = (const float*)d_in[9];
    const float* a_dst2 = (const float*)d_in[10];
    const float* b2     = (const float*)d_in[11];
    float* out = (float*)d_out;

    char* ws = (char*)d_ws;
    size_t off = 0;
    auto alloc = [&](size_t bytes) { char* p = ws + off; off += (bytes + 255) & ~size_t(255); return p; };
    float* h1     = (float*)alloc((size_t)N_NODES * 128 * 4);   // 25.6 MB (h2 [N,64] reuses this after gather1)
    float* out1   = (float*)alloc((size_t)N_NODES * 128 * 4);   // 25.6 MB (h0 [N,32] shares: dead before gather1 writes)
    float* ew     = (float*)alloc((size_t)N_EDGES * 4 * 4);     // 12.8 MB (reused both layers)
    float* as     = (float*)alloc((size_t)N_NODES * 4 * 4);
    float* ad     = (float*)alloc((size_t)N_NODES * 4 * 4);
    float* ssum   = (float*)alloc((size_t)N_NODES * 4 * 4);
    int*   counts = (int*)alloc((size_t)N_NODES * 4);
    int*   rowptr = (int*)alloc((size_t)(N_NODES + 1) * 4);
    int*   cursor = (int*)alloc((size_t)N_NODES * 4);
    int*   eidx   = (int*)alloc((size_t)N_EDGES * 4);
    float* h0     = out1;  // h0 [N,32]: written by k_emb, consumed by k_h1, dead before k_gather1 writes out1
    float* h2     = h1;    // h2 [N,64]: written by k_h2 after h1 is dead (post k_gather1)

    const int EB = (N_EDGES + 255) / 256;   // 3125
    const int AB = (N_NODES * HEADS + 255) / 256;

    // --- CSR build (dst-grouped edge list), reused by both layers
    hipMemsetAsync(counts, 0, (size_t)N_NODES * 4, stream);
    k_count<<<EB, 256, 0, stream>>>(ei, counts);
    k_scan<<<1, 1024, 0, stream>>>(counts, rowptr);
    hipMemcpyAsync(cursor, rowptr, (size_t)N_NODES * 4, hipMemcpyDeviceToDevice, stream);
    k_fill<<<EB, 256, 0, stream>>>(ei, cursor, eidx);

    // --- embedding + layer-1 features
    k_emb<<<N_NODES / 8, 256, 0, stream>>>(x, Wemb, bemb, h0);
    k_h1<<<N_NODES / 2, 256, 0, stream>>>(h0, W1, h1);
    k_alpha<HID><<<AB, 256, 0, stream>>>(h1, a_src1, a_dst1, as, ad);

    // --- layer-1 softmax denominators + aggregation (+b1, ELU fused)
    hipMemsetAsync(ssum, 0, (size_t)N_NODES * 4 * 4, stream);
    k_edge_sum<<<EB, 256, 0, stream>>>(ei, as, ad, ew, ssum);
    k_gather1<<<N_NODES / 2, 256, 0, stream>>>(ei, rowptr, eidx, h1, ew, ssum, b1, out1);

    // --- layer-2 features
    k_h2<<<N_NODES / 4, 256, 0, stream>>>(out1, W2, h2);
    k_alpha<OUT_C><<<AB, 256, 0, stream>>>(h2, a_src2, a_dst2, as, ad);

    // --- layer-2 softmax + aggregation + head-mean + b2 + log_softmax (fused)
    hipMemsetAsync(ssum, 0, (size_t)N_NODES * 4 * 4, stream);
    k_edge_sum<<<EB, 256, 0, stream>>>(ei, as, ad, ew, ssum);
    k_gather2<<<N_NODES / 4, 256, 0, stream>>>(ei, rowptr, eidx, h2, ew, ssum, b2, out);
}

// Round 3
// 396.332 us; speedup vs baseline: 2.7650x; 2.7650x over previous
//
#include <hip/hip_runtime.h>

#define N_NODES 50000
#define N_EDGES 800000
#define F_IN    128
#define HID     32
#define HEADS   4
#define OUT_C   16

// ================================================================ CSR build
__global__ __launch_bounds__(256) void k_count(const int* __restrict__ ei, int* __restrict__ counts) {
    int e = blockIdx.x * 256 + threadIdx.x;
    if (e >= N_EDGES) return;
    atomicAdd(&counts[ei[N_EDGES + e]], 1);
}

// single-block 1024-thread scan, shuffle-based (3 barriers per 1024-chunk)
__global__ __launch_bounds__(1024) void k_scan(const int* __restrict__ counts, int* __restrict__ rowptr) {
    __shared__ int wsum[16];
    __shared__ int carry_s;
    int t = threadIdx.x, lane = t & 63, wv = t >> 6;
    if (t == 0) carry_s = 0;
    __syncthreads();
    for (int base = 0; base < N_NODES; base += 1024) {
        int i = base + t;
        int v = (i < N_NODES) ? counts[i] : 0;
        int x = v;
        #pragma unroll
        for (int off = 1; off < 64; off <<= 1) {
            int y = __shfl_up(x, off, 64);
            if (lane >= off) x += y;
        }
        if (lane == 63) wsum[wv] = x;
        __syncthreads();
        int carry = carry_s;
        if (t < 16) {
            int w = wsum[t];
            #pragma unroll
            for (int off = 1; off < 16; off <<= 1) {
                int y = __shfl_up(w, off, 64);
                if (t >= off) w += y;
            }
            wsum[t] = w;   // inclusive wave totals
        }
        __syncthreads();
        int woff = (wv == 0) ? 0 : wsum[wv - 1];
        int incl = x + woff + carry;
        if (i < N_NODES) rowptr[i] = incl - v;   // exclusive scan
        __syncthreads();
        if (t == 1023) carry_s = incl;
        __syncthreads();
    }
    if (t == 0) rowptr[N_NODES] = carry_s;
}

// scatter src ids into dst-sorted order
__global__ __launch_bounds__(256) void k_fill(const int* __restrict__ ei, int* __restrict__ cursor,
                                              int* __restrict__ esrc) {
    int e = blockIdx.x * 256 + threadIdx.x;
    if (e >= N_EDGES) return;
    int d = ei[N_EDGES + e];
    int pos = atomicAdd(&cursor[d], 1);
    esrc[pos] = ei[e];
}

// ================================================================ GEMM: h0 = x @ Wemb + bemb   [N,128]x[128,32]
// 64 nodes/block; thread: c=t&7 (4 cols), g=t>>3, 2 nodes
__global__ __launch_bounds__(256) void k_emb(const float* __restrict__ x,
                                             const float* __restrict__ Wemb,
                                             const float* __restrict__ bemb,
                                             float* __restrict__ h0) {
    __shared__ float xs[64][132];      // pad 132: 16B-aligned rows, conflict-free
    __shared__ float Wl[F_IN][HID];    // 16 KB
    __shared__ float bl[HID];
    int t = threadIdx.x;
    int node0 = blockIdx.x * 64;
    if (t < HID) bl[t] = bemb[t];
    #pragma unroll
    for (int it = 0; it < 4; it++) {   // 128*32/4 = 1024 float4
        int idx = it * 256 + t;
        *(float4*)((float*)Wl + idx * 4) = *(const float4*)(Wemb + idx * 4);
    }
    #pragma unroll
    for (int it = 0; it < 8; it++) {   // 64*128/4 = 2048 float4
        int idx = it * 256 + t;
        int row = idx >> 5, c4 = idx & 31;
        float4 v = make_float4(0.f, 0.f, 0.f, 0.f);
        if (node0 + row < N_NODES) v = *(const float4*)(x + (size_t)(node0 + row) * F_IN + c4 * 4);
        *(float4*)&xs[row][c4 * 4] = v;
    }
    __syncthreads();
    int c = t & 7, g = t >> 3;
    float acc[2][4] = {};
    for (int k = 0; k < F_IN; k++) {
        float4 w4 = *(const float4*)&Wl[k][c * 4];
        #pragma unroll
        for (int n = 0; n < 2; n++) {
            float xv = xs[g * 2 + n][k];
            acc[n][0] += xv * w4.x; acc[n][1] += xv * w4.y;
            acc[n][2] += xv * w4.z; acc[n][3] += xv * w4.w;
        }
    }
    #pragma unroll
    for (int n = 0; n < 2; n++) {
        int node = node0 + g * 2 + n;
        if (node < N_NODES) {
            float4 o = make_float4(acc[n][0] + bl[c * 4], acc[n][1] + bl[c * 4 + 1],
                                   acc[n][2] + bl[c * 4 + 2], acc[n][3] + bl[c * 4 + 3]);
            *(float4*)(h0 + (size_t)node * HID + c * 4) = o;
        }
    }
}

// ================================================================ GEMM: h1 = h0 @ W1   [N,32]x[32,128]
// 64 nodes/block; thread: c=t&31 (4 cols), g=t>>5, 8 nodes
__global__ __launch_bounds__(256) void k_h1(const float* __restrict__ h0,
                                            const float* __restrict__ W1,
                                            float* __restrict__ h1) {
    __shared__ float xs[64][36];           // pad 36: 16B-aligned
    __shared__ float Wl[HID][128];         // 16 KB
    int t = threadIdx.x;
    int node0 = blockIdx.x * 64;
    #pragma unroll
    for (int it = 0; it < 4; it++) {       // 32*128/4 = 1024 float4
        int idx = it * 256 + t;
        *(float4*)((float*)Wl + idx * 4) = *(const float4*)(W1 + idx * 4);
    }
    #pragma unroll
    for (int it = 0; it < 2; it++) {       // 64*32/4 = 512 float4
        int idx = it * 256 + t;
        int row = idx >> 3, c4 = idx & 7;
        float4 v = make_float4(0.f, 0.f, 0.f, 0.f);
        if (node0 + row < N_NODES) v = *(const float4*)(h0 + (size_t)(node0 + row) * HID + c4 * 4);
        *(float4*)&xs[row][c4 * 4] = v;
    }
    __syncthreads();
    int c = t & 31, g = t >> 5;
    float acc[8][4] = {};
    for (int k = 0; k < HID; k++) {
        float4 w4 = *(const float4*)&Wl[k][c * 4];
        #pragma unroll
        for (int n = 0; n < 8; n++) {
            float xv = xs[g * 8 + n][k];
            acc[n][0] += xv * w4.x; acc[n][1] += xv * w4.y;
            acc[n][2] += xv * w4.z; acc[n][3] += xv * w4.w;
        }
    }
    #pragma unroll
    for (int n = 0; n < 8; n++) {
        int node = node0 + g * 8 + n;
        if (node < N_NODES)
            *(float4*)(h1 + (size_t)node * 128 + c * 4) =
                make_float4(acc[n][0], acc[n][1], acc[n][2], acc[n][3]);
    }
}

// ================================================================ GEMM: h2 = out1 @ W2   [N,128]x[128,64]
// 64 nodes/block; thread: c=t&15 (4 cols), g=t>>4, 4 nodes
__global__ __launch_bounds__(256) void k_h2(const float* __restrict__ hin,
                                            const float* __restrict__ W2,
                                            float* __restrict__ h2) {
    __shared__ float xs[64][132];
    __shared__ float Wl[128][64];          // 32 KB
    int t = threadIdx.x;
    int node0 = blockIdx.x * 64;
    #pragma unroll
    for (int it = 0; it < 8; it++) {       // 128*64/4 = 2048 float4
        int idx = it * 256 + t;
        *(float4*)((float*)Wl + idx * 4) = *(const float4*)(W2 + idx * 4);
    }
    #pragma unroll
    for (int it = 0; it < 8; it++) {       // 64*128/4 = 2048 float4
        int idx = it * 256 + t;
        int row = idx >> 5, c4 = idx & 31;
        float4 v = make_float4(0.f, 0.f, 0.f, 0.f);
        if (node0 + row < N_NODES) v = *(const float4*)(hin + (size_t)(node0 + row) * 128 + c4 * 4);
        *(float4*)&xs[row][c4 * 4] = v;
    }
    __syncthreads();
    int c = t & 15, g = t >> 4;
    float acc[4][4] = {};
    for (int k = 0; k < 128; k++) {
        float4 w4 = *(const float4*)&Wl[k][c * 4];
        #pragma unroll
        for (int n = 0; n < 4; n++) {
            float xv = xs[g * 4 + n][k];
            acc[n][0] += xv * w4.x; acc[n][1] += xv * w4.y;
            acc[n][2] += xv * w4.z; acc[n][3] += xv * w4.w;
        }
    }
    #pragma unroll
    for (int n = 0; n < 4; n++) {
        int node = node0 + g * 4 + n;
        if (node < N_NODES)
            *(float4*)(h2 + (size_t)node * 64 + c * 4) =
                make_float4(acc[n][0], acc[n][1], acc[n][2], acc[n][3]);
    }
}

// ================================================================ alpha dots
template <int C>
__global__ __launch_bounds__(256) void k_alpha(const float* __restrict__ h,
                                               const float* __restrict__ a_src,
                                               const float* __restrict__ a_dst,
                                               float* __restrict__ as, float* __restrict__ ad) {
    int t = blockIdx.x * 256 + threadIdx.x;
    if (t >= N_NODES * HEADS) return;
    int hh = t & (HEADS - 1);
    const float* hp = h + (size_t)t * C;
    float s0 = 0.f, s1 = 0.f;
    #pragma unroll
    for (int c = 0; c < C; c++) {
        float v = hp[c];
        s0 += v * a_src[hh * C + c];
        s1 += v * a_dst[hh * C + c];
    }
    as[t] = s0;
    ad[t] = s1;
}

__device__ __forceinline__ float edge_w(float asv, float adv) {
    float v = asv + adv;
    v = (v > 0.f) ? v : 0.2f * v;        // leaky_relu(0.2)
    return __expf(v);                    // softmax shift-invariant; logits O(1)
}

// ================================================================ layer-1 gather: one wave per node, float2 channels
__global__ __launch_bounds__(256) void k_gather1(const int* __restrict__ esrc,
                                                 const int* __restrict__ rowptr,
                                                 const float* __restrict__ h1,
                                                 const float* __restrict__ as,
                                                 const float* __restrict__ ad,
                                                 const float* __restrict__ b1,
                                                 float* __restrict__ out1) {
    int t = threadIdx.x;
    int node = blockIdx.x * 4 + (t >> 6);
    int lane = t & 63;
    int ch = 2 * lane;                   // channels ch, ch+1
    int head = lane >> 4;
    int beg = rowptr[node], end = rowptr[node + 1];
    float adn = ad[node * 4 + head];
    float ax = 0.f, ay = 0.f, s = 0.f;
    int k = beg;
    for (; k + 4 <= end; k += 4) {
        int s0 = esrc[k], s1 = esrc[k + 1], s2 = esrc[k + 2], s3 = esrc[k + 3];
        float w0 = edge_w(as[s0 * 4 + head], adn);
        float w1 = edge_w(as[s1 * 4 + head], adn);
        float w2 = edge_w(as[s2 * 4 + head], adn);
        float w3 = edge_w(as[s3 * 4 + head], adn);
        float2 r0 = *(const float2*)(h1 + (size_t)s0 * 128 + ch);
        float2 r1 = *(const float2*)(h1 + (size_t)s1 * 128 + ch);
        float2 r2 = *(const float2*)(h1 + (size_t)s2 * 128 + ch);
        float2 r3 = *(const float2*)(h1 + (size_t)s3 * 128 + ch);
        ax += r0.x * w0 + r1.x * w1 + r2.x * w2 + r3.x * w3;
        ay += r0.y * w0 + r1.y * w1 + r2.y * w2 + r3.y * w3;
        s += w0 + w1 + w2 + w3;
    }
    for (; k < end; k++) {
        int sv = esrc[k];
        float w = edge_w(as[sv * 4 + head], adn);
        float2 r = *(const float2*)(h1 + (size_t)sv * 128 + ch);
        ax += r.x * w; ay += r.y * w; s += w;
    }
    float rs = 1.0f / (s + 1e-16f);
    float2 bv = *(const float2*)(b1 + ch);
    float vx = ax * rs + bv.x;
    float vy = ay * rs + bv.y;
    vx = (vx > 0.f) ? vx : (__expf(vx) - 1.0f);   // ELU
    vy = (vy > 0.f) ? vy : (__expf(vy) - 1.0f);
    *(float2*)(out1 + (size_t)node * 128 + ch) = make_float2(vx, vy);
}

// ================================================================ layer-2 gather + head-mean + b2 + log_softmax
__global__ __launch_bounds__(256) void k_gather2(const int* __restrict__ esrc,
                                                 const int* __restrict__ rowptr,
                                                 const float* __restrict__ h2,
                                                 const float* __restrict__ as,
                                                 const float* __restrict__ ad,
                                                 const float* __restrict__ b2,
                                                 float* __restrict__ out) {
    int t = threadIdx.x;
    int node = blockIdx.x * 4 + (t >> 6);
    int lane = t & 63;
    int head = lane >> 4, c = lane & 15;
    int beg = rowptr[node], end = rowptr[node + 1];
    float adn = ad[node * 4 + head];
    float acc = 0.f, s = 0.f;
    int k = beg;
    for (; k + 4 <= end; k += 4) {
        int s0 = esrc[k], s1 = esrc[k + 1], s2 = esrc[k + 2], s3 = esrc[k + 3];
        float w0 = edge_w(as[s0 * 4 + head], adn);
        float w1 = edge_w(as[s1 * 4 + head], adn);
        float w2 = edge_w(as[s2 * 4 + head], adn);
        float w3 = edge_w(as[s3 * 4 + head], adn);
        float r0 = h2[(size_t)s0 * 64 + lane];
        float r1 = h2[(size_t)s1 * 64 + lane];
        float r2 = h2[(size_t)s2 * 64 + lane];
        float r3 = h2[(size_t)s3 * 64 + lane];
        acc += r0 * w0 + r1 * w1 + r2 * w2 + r3 * w3;
        s += w0 + w1 + w2 + w3;
    }
    for (; k < end; k++) {
        int sv = esrc[k];
        float w = edge_w(as[sv * 4 + head], adn);
        acc += h2[(size_t)sv * 64 + lane] * w;
        s += w;
    }
    float v = acc * (1.0f / (s + 1e-16f));
    // mean over 4 heads (lanes lane, lane^16, lane^32 hold same c)
    v += __shfl_xor(v, 16, 64);
    v += __shfl_xor(v, 32, 64);
    v = v * 0.25f + b2[c];
    // log_softmax over 16 classes within each 16-lane group
    float m = v;
    #pragma unroll
    for (int mask = 1; mask < 16; mask <<= 1) m = fmaxf(m, __shfl_xor(m, mask, 64));
    float ex = __expf(v - m);
    float se = ex;
    #pragma unroll
    for (int mask = 1; mask < 16; mask <<= 1) se += __shfl_xor(se, mask, 64);
    float res = (v - m) - __logf(se);
    if (lane < 16) out[(size_t)node * 16 + lane] = res;
}

// ================================================================ host
extern "C" void kernel_launch(void* const* d_in, const int* in_sizes, int n_in,
                              void* d_out, int out_size, void* d_ws, size_t ws_size,
                              hipStream_t stream) {
    const float* x      = (const float*)d_in[0];
    const int*   ei     = (const int*)d_in[1];
    const float* Wemb   = (const float*)d_in[2];
    const float* bemb   = (const float*)d_in[3];
    const float* W1     = (const float*)d_in[4];
    const float* a_src1 = (const float*)d_in[5];
    const float* a_dst1 = (const float*)d_in[6];
    const float* b1     = (const float*)d_in[7];
    const float* W2     = (const float*)d_in[8];
    const float* a_src2 = (const float*)d_in[9];
    const float* a_dst2 = (const float*)d_in[10];
    const float* b2     = (const float*)d_in[11];
    float* out = (float*)d_out;

    char* ws = (char*)d_ws;
    size_t off = 0;
    auto alloc = [&](size_t bytes) { char* p = ws + off; off += (bytes + 255) & ~size_t(255); return p; };
    float* h1     = (float*)alloc((size_t)N_NODES * 128 * 4);   // h2 [N,64] overlays after gather1
    float* out1   = (float*)alloc((size_t)N_NODES * 128 * 4);   // h0 [N,32] overlays before gather1
    int*   esrc   = (int*)alloc((size_t)N_EDGES * 4);
    float* as     = (float*)alloc((size_t)N_NODES * 4 * 4);
    float* ad     = (float*)alloc((size_t)N_NODES * 4 * 4);
    int*   counts = (int*)alloc((size_t)N_NODES * 4);
    int*   rowptr = (int*)alloc((size_t)(N_NODES + 1) * 4);
    int*   cursor = (int*)alloc((size_t)N_NODES * 4);
    float* h0     = out1;  // dead before gather1 writes out1
    float* h2     = h1;    // h1 dead after gather1

    const int EB   = (N_EDGES + 255) / 256;          // 3125
    const int AB   = (N_NODES * HEADS + 255) / 256;  // 782
    const int NB64 = (N_NODES + 63) / 64;            // 782
    const int GB   = N_NODES / 4;                    // 12500

    // --- CSR (dst-sorted src list), reused by both layers
    hipMemsetAsync(counts, 0, (size_t)N_NODES * 4, stream);
    k_count<<<EB, 256, 0, stream>>>(ei, counts);
    k_scan<<<1, 1024, 0, stream>>>(counts, rowptr);
    hipMemcpyAsync(cursor, rowptr, (size_t)N_NODES * 4, hipMemcpyDeviceToDevice, stream);
    k_fill<<<EB, 256, 0, stream>>>(ei, cursor, esrc);

    // --- features + layer 1
    k_emb<<<NB64, 256, 0, stream>>>(x, Wemb, bemb, h0);
    k_h1<<<NB64, 256, 0, stream>>>(h0, W1, h1);
    k_alpha<HID><<<AB, 256, 0, stream>>>(h1, a_src1, a_dst1, as, ad);
    k_gather1<<<GB, 256, 0, stream>>>(esrc, rowptr, h1, as, ad, b1, out1);

    // --- layer 2 (softmax+aggregate+mean+log_softmax fused in gather2)
    k_h2<<<NB64, 256, 0, stream>>>(out1, W2, h2);
    k_alpha<OUT_C><<<AB, 256, 0, stream>>>(h2, a_src2, a_dst2, as, ad);
    k_gather2<<<GB, 256, 0, stream>>>(esrc, rowptr, h2, as, ad, b2, out);
}

// Round 4
// 312.111 us; speedup vs baseline: 3.5111x; 1.2698x over previous
//
#include <hip/hip_runtime.h>

#define N_NODES 50000
#define N_EDGES 800000
#define F_IN    128
#define HID     32
#define HEADS   4
#define OUT_C   16
#define SCAN_BLOCKS 196   // 196*256 = 50176 >= N_NODES

// bf16 helpers (RNE), raw-bit based to avoid header API differences
__device__ __forceinline__ unsigned short f2bf(float f) {
    unsigned int u = __float_as_uint(f);
    u += 0x7FFFu + ((u >> 16) & 1u);
    return (unsigned short)(u >> 16);
}
__device__ __forceinline__ float bf2f(unsigned short s) {
    return __uint_as_float(((unsigned int)s) << 16);
}

// ================================================================ CSR build
__global__ __launch_bounds__(256) void k_count(const int* __restrict__ ei, int* __restrict__ counts) {
    int e = blockIdx.x * 256 + threadIdx.x;
    if (e >= N_EDGES) return;
    atomicAdd(&counts[ei[N_EDGES + e]], 1);
}

// parallel scan, 3 kernels: per-block scan -> scan block totals -> add offsets
__global__ __launch_bounds__(256) void k_scanA(const int* __restrict__ counts,
                                               int* __restrict__ rowptr, int* __restrict__ totals) {
    int t = threadIdx.x, lane = t & 63, wv = t >> 6;
    int i = blockIdx.x * 256 + t;
    int v = (i < N_NODES) ? counts[i] : 0;
    int x = v;
    #pragma unroll
    for (int off = 1; off < 64; off <<= 1) { int y = __shfl_up(x, off, 64); if (lane >= off) x += y; }
    __shared__ int ws[4];
    if (lane == 63) ws[wv] = x;
    __syncthreads();
    int add = 0;
    for (int j = 0; j < wv; j++) add += ws[j];
    if (i < N_NODES) rowptr[i] = x - v + add;       // block-local exclusive
    if (t == 255) totals[blockIdx.x] = x + add;     // block total
}

__global__ __launch_bounds__(256) void k_scanB(const int* __restrict__ totals,
                                               int* __restrict__ boffs, int* __restrict__ rowptr) {
    int t = threadIdx.x, lane = t & 63, wv = t >> 6;
    int v = (t < SCAN_BLOCKS) ? totals[t] : 0;
    int x = v;
    #pragma unroll
    for (int off = 1; off < 64; off <<= 1) { int y = __shfl_up(x, off, 64); if (lane >= off) x += y; }
    __shared__ int ws[4];
    if (lane == 63) ws[wv] = x;
    __syncthreads();
    int add = 0;
    for (int j = 0; j < wv; j++) add += ws[j];
    if (t < SCAN_BLOCKS) boffs[t] = x - v + add;
    if (t == 255) rowptr[N_NODES] = x + add;        // grand total = N_EDGES
}

__global__ __launch_bounds__(256) void k_scanC(int* __restrict__ rowptr, int* __restrict__ cursor,
                                               const int* __restrict__ boffs) {
    int i = blockIdx.x * 256 + threadIdx.x;
    if (i >= N_NODES) return;
    int r = rowptr[i] + boffs[blockIdx.x];
    rowptr[i] = r;
    cursor[i] = r;
}

__global__ __launch_bounds__(256) void k_fill(const int* __restrict__ ei, int* __restrict__ cursor,
                                              int* __restrict__ esrc) {
    int e = blockIdx.x * 256 + threadIdx.x;
    if (e >= N_EDGES) return;
    int d = ei[N_EDGES + e];
    int pos = atomicAdd(&cursor[d], 1);
    esrc[pos] = ei[e];
}

// ================================================================ GEMM: h0 = x @ Wemb + bemb   [N,128]x[128,32]
__global__ __launch_bounds__(256) void k_emb(const float* __restrict__ x,
                                             const float* __restrict__ Wemb,
                                             const float* __restrict__ bemb,
                                             float* __restrict__ h0) {
    __shared__ float xs[64][132];
    __shared__ float Wl[F_IN][HID];
    __shared__ float bl[HID];
    int t = threadIdx.x;
    int node0 = blockIdx.x * 64;
    if (t < HID) bl[t] = bemb[t];
    #pragma unroll
    for (int it = 0; it < 4; it++) {
        int idx = it * 256 + t;
        *(float4*)((float*)Wl + idx * 4) = *(const float4*)(Wemb + idx * 4);
    }
    #pragma unroll
    for (int it = 0; it < 8; it++) {
        int idx = it * 256 + t;
        int row = idx >> 5, c4 = idx & 31;
        float4 v = make_float4(0.f, 0.f, 0.f, 0.f);
        if (node0 + row < N_NODES) v = *(const float4*)(x + (size_t)(node0 + row) * F_IN + c4 * 4);
        *(float4*)&xs[row][c4 * 4] = v;
    }
    __syncthreads();
    int c = t & 7, g = t >> 3;
    float acc[2][4] = {};
    for (int k = 0; k < F_IN; k++) {
        float4 w4 = *(const float4*)&Wl[k][c * 4];
        #pragma unroll
        for (int n = 0; n < 2; n++) {
            float xv = xs[g * 2 + n][k];
            acc[n][0] += xv * w4.x; acc[n][1] += xv * w4.y;
            acc[n][2] += xv * w4.z; acc[n][3] += xv * w4.w;
        }
    }
    #pragma unroll
    for (int n = 0; n < 2; n++) {
        int node = node0 + g * 2 + n;
        if (node < N_NODES) {
            float4 o = make_float4(acc[n][0] + bl[c * 4], acc[n][1] + bl[c * 4 + 1],
                                   acc[n][2] + bl[c * 4 + 2], acc[n][3] + bl[c * 4 + 3]);
            *(float4*)(h0 + (size_t)node * HID + c * 4) = o;
        }
    }
}

// ================================================================ h1 = h0 @ W1 (bf16 out) + fused alpha1 dots
__global__ __launch_bounds__(256) void k_h1f(const float* __restrict__ h0,
                                             const float* __restrict__ W1,
                                             const float* __restrict__ a_src,
                                             const float* __restrict__ a_dst,
                                             unsigned short* __restrict__ h1,
                                             float* __restrict__ as, float* __restrict__ ad) {
    __shared__ float xs[64][36];
    __shared__ float Wl[HID][128];
    int t = threadIdx.x;
    int node0 = blockIdx.x * 64;
    #pragma unroll
    for (int it = 0; it < 4; it++) {
        int idx = it * 256 + t;
        *(float4*)((float*)Wl + idx * 4) = *(const float4*)(W1 + idx * 4);
    }
    #pragma unroll
    for (int it = 0; it < 2; it++) {
        int idx = it * 256 + t;
        int row = idx >> 3, c4 = idx & 7;
        float4 v = make_float4(0.f, 0.f, 0.f, 0.f);
        if (node0 + row < N_NODES) v = *(const float4*)(h0 + (size_t)(node0 + row) * HID + c4 * 4);
        *(float4*)&xs[row][c4 * 4] = v;
    }
    __syncthreads();
    int c = t & 31, g = t >> 5;
    float acc[8][4] = {};
    for (int k = 0; k < HID; k++) {
        float4 w4 = *(const float4*)&Wl[k][c * 4];
        #pragma unroll
        for (int n = 0; n < 8; n++) {
            float xv = xs[g * 8 + n][k];
            acc[n][0] += xv * w4.x; acc[n][1] += xv * w4.y;
            acc[n][2] += xv * w4.z; acc[n][3] += xv * w4.w;
        }
    }
    // bf16 table write + alpha partials (fp32 accs -> full accuracy logits)
    float4 av = *(const float4*)(a_src + c * 4);   // flat [4][32] == col index
    float4 dv = *(const float4*)(a_dst + c * 4);
    float ps[8], pd[8];
    #pragma unroll
    for (int n = 0; n < 8; n++) {
        int node = node0 + g * 8 + n;
        if (node < N_NODES) {
            ushort4 o;
            o.x = f2bf(acc[n][0]); o.y = f2bf(acc[n][1]);
            o.z = f2bf(acc[n][2]); o.w = f2bf(acc[n][3]);
            *(ushort4*)(h1 + (size_t)node * 128 + c * 4) = o;
        }
        ps[n] = acc[n][0] * av.x + acc[n][1] * av.y + acc[n][2] * av.z + acc[n][3] * av.w;
        pd[n] = acc[n][0] * dv.x + acc[n][1] * dv.y + acc[n][2] * dv.z + acc[n][3] * dv.w;
    }
    #pragma unroll
    for (int mask = 1; mask <= 4; mask <<= 1) {
        #pragma unroll
        for (int n = 0; n < 8; n++) {
            ps[n] += __shfl_xor(ps[n], mask, 64);
            pd[n] += __shfl_xor(pd[n], mask, 64);
        }
    }
    if ((c & 7) == 0) {
        int hh = c >> 3;
        #pragma unroll
        for (int n = 0; n < 8; n++) {
            int node = node0 + g * 8 + n;
            if (node < N_NODES) { as[node * 4 + hh] = ps[n]; ad[node * 4 + hh] = pd[n]; }
        }
    }
}

// ================================================================ h2 = out1 @ W2 (bf16 out) + fused alpha2 dots
__global__ __launch_bounds__(256) void k_h2f(const float* __restrict__ hin,
                                             const float* __restrict__ W2,
                                             const float* __restrict__ a_src,
                                             const float* __restrict__ a_dst,
                                             unsigned short* __restrict__ h2,
                                             float* __restrict__ as, float* __restrict__ ad) {
    __shared__ float xs[64][132];
    __shared__ float Wl[128][64];
    int t = threadIdx.x;
    int node0 = blockIdx.x * 64;
    #pragma unroll
    for (int it = 0; it < 8; it++) {
        int idx = it * 256 + t;
        *(float4*)((float*)Wl + idx * 4) = *(const float4*)(W2 + idx * 4);
    }
    #pragma unroll
    for (int it = 0; it < 8; it++) {
        int idx = it * 256 + t;
        int row = idx >> 5, c4 = idx & 31;
        float4 v = make_float4(0.f, 0.f, 0.f, 0.f);
        if (node0 + row < N_NODES) v = *(const float4*)(hin + (size_t)(node0 + row) * 128 + c4 * 4);
        *(float4*)&xs[row][c4 * 4] = v;
    }
    __syncthreads();
    int c = t & 15, g = t >> 4;
    float acc[4][4] = {};
    for (int k = 0; k < 128; k++) {
        float4 w4 = *(const float4*)&Wl[k][c * 4];
        #pragma unroll
        for (int n = 0; n < 4; n++) {
            float xv = xs[g * 4 + n][k];
            acc[n][0] += xv * w4.x; acc[n][1] += xv * w4.y;
            acc[n][2] += xv * w4.z; acc[n][3] += xv * w4.w;
        }
    }
    float4 av = *(const float4*)(a_src + c * 4);   // flat [4][16] == col index
    float4 dv = *(const float4*)(a_dst + c * 4);
    float ps[4], pd[4];
    #pragma unroll
    for (int n = 0; n < 4; n++) {
        int node = node0 + g * 4 + n;
        if (node < N_NODES) {
            ushort4 o;
            o.x = f2bf(acc[n][0]); o.y = f2bf(acc[n][1]);
            o.z = f2bf(acc[n][2]); o.w = f2bf(acc[n][3]);
            *(ushort4*)(h2 + (size_t)node * 64 + c * 4) = o;
        }
        ps[n] = acc[n][0] * av.x + acc[n][1] * av.y + acc[n][2] * av.z + acc[n][3] * av.w;
        pd[n] = acc[n][0] * dv.x + acc[n][1] * dv.y + acc[n][2] * dv.z + acc[n][3] * dv.w;
    }
    #pragma unroll
    for (int mask = 1; mask <= 2; mask <<= 1) {
        #pragma unroll
        for (int n = 0; n < 4; n++) {
            ps[n] += __shfl_xor(ps[n], mask, 64);
            pd[n] += __shfl_xor(pd[n], mask, 64);
        }
    }
    if ((c & 3) == 0) {
        int hh = c >> 2;
        #pragma unroll
        for (int n = 0; n < 4; n++) {
            int node = node0 + g * 4 + n;
            if (node < N_NODES) { as[node * 4 + hh] = ps[n]; ad[node * 4 + hh] = pd[n]; }
        }
    }
}

__device__ __forceinline__ float edge_w(float asv, float adv) {
    float v = asv + adv;
    v = (v > 0.f) ? v : 0.2f * v;        // leaky_relu(0.2)
    return __expf(v);                    // softmax shift-invariant; logits O(1)
}

// ================================================================ layer-1 gather (bf16 table, shuffle-shared w)
__global__ __launch_bounds__(256) void k_gather1(const int* __restrict__ esrc,
                                                 const int* __restrict__ rowptr,
                                                 const unsigned int* __restrict__ h1,   // bf16x2 words, 64/row
                                                 const float* __restrict__ as,
                                                 const float* __restrict__ ad,
                                                 const float* __restrict__ b1,
                                                 float* __restrict__ out1) {
    int t = threadIdx.x;
    int node = blockIdx.x * 4 + (t >> 6);
    int lane = t & 63;
    int head = lane >> 4;
    int i4 = (lane >> 2) & 3;            // edge slot this lane computes w for
    int h4 = lane & 3;                   // head this lane computes w for
    int beg = rowptr[node], end = rowptr[node + 1];
    float ad_w = ad[node * 4 + h4];
    float adn = __shfl(ad_w, head, 64);
    float ax = 0.f, ay = 0.f, s = 0.f;
    int k = beg;
    for (; k + 4 <= end; k += 4) {
        int s0 = esrc[k], s1 = esrc[k + 1], s2 = esrc[k + 2], s3 = esrc[k + 3];
        int sm = (i4 < 2) ? (i4 == 0 ? s0 : s1) : (i4 == 2 ? s2 : s3);
        float wm = edge_w(as[sm * 4 + h4], ad_w);       // lanes 0-15 carry the 16 (edge,head) w's
        float w0 = __shfl(wm, head, 64);
        float w1 = __shfl(wm, 4 | head, 64);
        float w2 = __shfl(wm, 8 | head, 64);
        float w3 = __shfl(wm, 12 | head, 64);
        unsigned int u0 = h1[(size_t)s0 * 64 + lane];
        unsigned int u1 = h1[(size_t)s1 * 64 + lane];
        unsigned int u2 = h1[(size_t)s2 * 64 + lane];
        unsigned int u3 = h1[(size_t)s3 * 64 + lane];
        ax += __uint_as_float(u0 << 16) * w0 + __uint_as_float(u1 << 16) * w1
            + __uint_as_float(u2 << 16) * w2 + __uint_as_float(u3 << 16) * w3;
        ay += __uint_as_float(u0 & 0xFFFF0000u) * w0 + __uint_as_float(u1 & 0xFFFF0000u) * w1
            + __uint_as_float(u2 & 0xFFFF0000u) * w2 + __uint_as_float(u3 & 0xFFFF0000u) * w3;
        s += w0 + w1 + w2 + w3;
    }
    for (; k < end; k++) {
        int sv = esrc[k];
        float w = edge_w(as[sv * 4 + head], adn);
        unsigned int u = h1[(size_t)sv * 64 + lane];
        ax += __uint_as_float(u << 16) * w;
        ay += __uint_as_float(u & 0xFFFF0000u) * w;
        s += w;
    }
    float rs = 1.0f / (s + 1e-16f);
    float2 bv = *(const float2*)(b1 + 2 * lane);
    float vx = ax * rs + bv.x;
    float vy = ay * rs + bv.y;
    vx = (vx > 0.f) ? vx : (__expf(vx) - 1.0f);   // ELU
    vy = (vy > 0.f) ? vy : (__expf(vy) - 1.0f);
    *(float2*)(out1 + (size_t)node * 128 + 2 * lane) = make_float2(vx, vy);
}

// ================================================================ layer-2 gather + head-mean + b2 + log_softmax
__global__ __launch_bounds__(256) void k_gather2(const int* __restrict__ esrc,
                                                 const int* __restrict__ rowptr,
                                                 const unsigned short* __restrict__ h2,  // bf16, 64/row
                                                 const float* __restrict__ as,
                                                 const float* __restrict__ ad,
                                                 const float* __restrict__ b2,
                                                 float* __restrict__ out) {
    int t = threadIdx.x;
    int node = blockIdx.x * 4 + (t >> 6);
    int lane = t & 63;
    int head = lane >> 4, c = lane & 15;
    int i4 = (lane >> 2) & 3;
    int h4 = lane & 3;
    int beg = rowptr[node], end = rowptr[node + 1];
    float ad_w = ad[node * 4 + h4];
    float adn = __shfl(ad_w, head, 64);
    float acc = 0.f, s = 0.f;
    int k = beg;
    for (; k + 4 <= end; k += 4) {
        int s0 = esrc[k], s1 = esrc[k + 1], s2 = esrc[k + 2], s3 = esrc[k + 3];
        int sm = (i4 < 2) ? (i4 == 0 ? s0 : s1) : (i4 == 2 ? s2 : s3);
        float wm = edge_w(as[sm * 4 + h4], ad_w);
        float w0 = __shfl(wm, head, 64);
        float w1 = __shfl(wm, 4 | head, 64);
        float w2 = __shfl(wm, 8 | head, 64);
        float w3 = __shfl(wm, 12 | head, 64);
        float r0 = bf2f(h2[(size_t)s0 * 64 + lane]);
        float r1 = bf2f(h2[(size_t)s1 * 64 + lane]);
        float r2 = bf2f(h2[(size_t)s2 * 64 + lane]);
        float r3 = bf2f(h2[(size_t)s3 * 64 + lane]);
        acc += r0 * w0 + r1 * w1 + r2 * w2 + r3 * w3;
        s += w0 + w1 + w2 + w3;
    }
    for (; k < end; k++) {
        int sv = esrc[k];
        float w = edge_w(as[sv * 4 + head], adn);
        acc += bf2f(h2[(size_t)sv * 64 + lane]) * w;
        s += w;
    }
    float v = acc * (1.0f / (s + 1e-16f));
    v += __shfl_xor(v, 16, 64);          // mean over 4 heads
    v += __shfl_xor(v, 32, 64);
    v = v * 0.25f + b2[c];
    float m = v;                         // log_softmax over 16 classes
    #pragma unroll
    for (int mask = 1; mask < 16; mask <<= 1) m = fmaxf(m, __shfl_xor(m, mask, 64));
    float ex = __expf(v - m);
    float se = ex;
    #pragma unroll
    for (int mask = 1; mask < 16; mask <<= 1) se += __shfl_xor(se, mask, 64);
    float res = (v - m) - __logf(se);
    if (lane < 16) out[(size_t)node * 16 + lane] = res;
}

// ================================================================ host
extern "C" void kernel_launch(void* const* d_in, const int* in_sizes, int n_in,
                              void* d_out, int out_size, void* d_ws, size_t ws_size,
                              hipStream_t stream) {
    const float* x      = (const float*)d_in[0];
    const int*   ei     = (const int*)d_in[1];
    const float* Wemb   = (const float*)d_in[2];
    const float* bemb   = (const float*)d_in[3];
    const float* W1     = (const float*)d_in[4];
    const float* a_src1 = (const float*)d_in[5];
    const float* a_dst1 = (const float*)d_in[6];
    const float* b1     = (const float*)d_in[7];
    const float* W2     = (const float*)d_in[8];
    const float* a_src2 = (const float*)d_in[9];
    const float* a_dst2 = (const float*)d_in[10];
    const float* b2     = (const float*)d_in[11];
    float* out = (float*)d_out;

    char* ws = (char*)d_ws;
    size_t off = 0;
    auto alloc = [&](size_t bytes) { char* p = ws + off; off += (bytes + 255) & ~size_t(255); return p; };
    float*          out1   = (float*)alloc((size_t)N_NODES * 128 * 4);   // h0 [N,32] overlays front
    unsigned short* h1b    = (unsigned short*)alloc((size_t)N_NODES * 128 * 2); // h2b [N,64] overlays front
    int*   esrc   = (int*)alloc((size_t)N_EDGES * 4);
    float* as     = (float*)alloc((size_t)N_NODES * 4 * 4);
    float* ad     = (float*)alloc((size_t)N_NODES * 4 * 4);
    int*   counts = (int*)alloc((size_t)N_NODES * 4);
    int*   rowptr = (int*)alloc((size_t)(N_NODES + 1) * 4);
    int*   cursor = (int*)alloc((size_t)N_NODES * 4);
    int*   totals = (int*)alloc((size_t)SCAN_BLOCKS * 4);
    int*   boffs  = (int*)alloc((size_t)SCAN_BLOCKS * 4);
    float*          h0  = out1;                   // dead before gather1 writes out1
    unsigned short* h2b = h1b;                    // h1b dead after gather1

    const int EB   = (N_EDGES + 255) / 256;       // 3125
    const int NB64 = (N_NODES + 63) / 64;         // 782
    const int GB   = N_NODES / 4;                 // 12500

    // --- CSR (dst-sorted src list), reused by both layers
    hipMemsetAsync(counts, 0, (size_t)N_NODES * 4, stream);
    k_count<<<EB, 256, 0, stream>>>(ei, counts);
    k_scanA<<<SCAN_BLOCKS, 256, 0, stream>>>(counts, rowptr, totals);
    k_scanB<<<1, 256, 0, stream>>>(totals, boffs, rowptr);
    k_scanC<<<SCAN_BLOCKS, 256, 0, stream>>>(rowptr, cursor, boffs);
    k_fill<<<EB, 256, 0, stream>>>(ei, cursor, esrc);

    // --- features + layer 1
    k_emb<<<NB64, 256, 0, stream>>>(x, Wemb, bemb, h0);
    k_h1f<<<NB64, 256, 0, stream>>>(h0, W1, a_src1, a_dst1, h1b, as, ad);
    k_gather1<<<GB, 256, 0, stream>>>(esrc, rowptr, (const unsigned int*)h1b, as, ad, b1, out1);

    // --- layer 2 (softmax+aggregate+mean+log_softmax fused in gather2)
    k_h2f<<<NB64, 256, 0, stream>>>(out1, W2, a_src2, a_dst2, h2b, as, ad);
    k_gather2<<<GB, 256, 0, stream>>>(esrc, rowptr, h2b, as, ad, b2, out);
}

// Round 5
// 246.614 us; speedup vs baseline: 4.4436x; 1.2656x over previous
//
#include <hip/hip_runtime.h>

#define N_NODES 50000
#define N_EDGES 800000
#define F_IN    128
#define HID     32
#define HEADS   4
#define OUT_C   16

#define NBKT 196      // buckets = dst>>8 ; 196*256 = 50176 >= N_NODES
#define CAP  5120     // per-bucket capacity; mean 4082, sigma 64 -> plenty
#define EPB  4096     // edges per phase-A block; 196 blocks cover 802816

// bf16 helpers (RNE)
__device__ __forceinline__ unsigned short f2bf(float f) {
    unsigned int u = __float_as_uint(f);
    u += 0x7FFFu + ((u >> 16) & 1u);
    return (unsigned short)(u >> 16);
}
__device__ __forceinline__ float bf2f(unsigned short s) {
    return __uint_as_float(((unsigned int)s) << 16);
}

// ================================================================ CSR build, bucketed
// Phase A: scatter packed (src<<8 | dst&255) into per-bucket regions.
__global__ __launch_bounds__(256) void k_bucketA(const int* __restrict__ ei,
                                                 int* __restrict__ gcnt,
                                                 unsigned int* __restrict__ pairs) {
    __shared__ int hist[NBKT];
    __shared__ int base[NBKT];
    int t = threadIdx.x;
    int e0 = blockIdx.x * EPB;
    for (int i = t; i < NBKT; i += 256) hist[i] = 0;
    __syncthreads();
    unsigned int p[16];
    int bb[16];
    #pragma unroll
    for (int i = 0; i < 16; i++) {
        int e = e0 + i * 256 + t;
        bb[i] = -1;
        if (e < N_EDGES) {
            int s = ei[e], d = ei[N_EDGES + e];
            p[i] = ((unsigned int)s << 8) | (unsigned int)(d & 255);
            bb[i] = d >> 8;
            atomicAdd(&hist[bb[i]], 1);
        }
    }
    __syncthreads();
    for (int i = t; i < NBKT; i += 256) {
        int c = hist[i];
        base[i] = i * CAP + (c ? atomicAdd(&gcnt[i], c) : 0);
        hist[i] = 0;   // reuse as cursor
    }
    __syncthreads();
    #pragma unroll
    for (int i = 0; i < 16; i++) {
        if (bb[i] >= 0) {
            int off = atomicAdd(&hist[bb[i]], 1);
            pairs[base[bb[i]] + off] = p[i];
        }
    }
}

// Phase S: exclusive scan of the 196 bucket totals (one block).
__global__ __launch_bounds__(256) void k_bucketS(const int* __restrict__ gcnt,
                                                 int* __restrict__ bbase) {
    __shared__ int wsum[4];
    int t = threadIdx.x, lane = t & 63, wv = t >> 6;
    int v = (t < NBKT) ? gcnt[t] : 0;
    int x = v;
    #pragma unroll
    for (int off = 1; off < 64; off <<= 1) { int y = __shfl_up(x, off, 64); if (lane >= off) x += y; }
    if (lane == 63) wsum[wv] = x;
    __syncthreads();
    int add = 0;
    for (int j = 0; j < wv; j++) add += wsum[j];
    if (t < NBKT) bbase[t] = x - v + add;
}

// Phase B: one block per bucket — local CSR (rowptr slice) + esrc scatter into an L2-resident window.
__global__ __launch_bounds__(256) void k_bucketB(const unsigned int* __restrict__ pairs,
                                                 const int* __restrict__ gcnt,
                                                 const int* __restrict__ bbase,
                                                 int* __restrict__ rowptr,
                                                 int* __restrict__ esrc) {
    __shared__ int cnt[256];
    __shared__ int cur[256];
    __shared__ int wsum[4];
    int b = blockIdx.x, t = threadIdx.x;
    int n0 = b << 8;
    int cntb = gcnt[b];
    int s0 = b * CAP;
    int base = bbase[b];
    cnt[t] = 0;
    __syncthreads();
    for (int i = t; i < cntb; i += 256) atomicAdd(&cnt[pairs[s0 + i] & 255], 1);
    __syncthreads();
    int lane = t & 63, wv = t >> 6;
    int v = cnt[t], x = v;
    #pragma unroll
    for (int off = 1; off < 64; off <<= 1) { int y = __shfl_up(x, off, 64); if (lane >= off) x += y; }
    if (lane == 63) wsum[wv] = x;
    __syncthreads();
    int add = 0;
    for (int j = 0; j < wv; j++) add += wsum[j];
    int excl = base + (x - v) + add;
    cur[t] = excl;
    if (n0 + t < N_NODES) rowptr[n0 + t] = excl;
    if (b == 0 && t == 0) rowptr[N_NODES] = N_EDGES;
    __syncthreads();
    for (int i = t; i < cntb; i += 256) {
        unsigned int p = pairs[s0 + i];
        int pos = atomicAdd(&cur[p & 255], 1);
        esrc[pos] = (int)(p >> 8);
    }
}

// ================================================================ GEMM: h0 = x @ Wemb + bemb   [N,128]x[128,32]
__global__ __launch_bounds__(256) void k_emb(const float* __restrict__ x,
                                             const float* __restrict__ Wemb,
                                             const float* __restrict__ bemb,
                                             float* __restrict__ h0) {
    __shared__ float xs[64][132];
    __shared__ float Wl[F_IN][HID];
    __shared__ float bl[HID];
    int t = threadIdx.x;
    int node0 = blockIdx.x * 64;
    if (t < HID) bl[t] = bemb[t];
    #pragma unroll
    for (int it = 0; it < 4; it++) {
        int idx = it * 256 + t;
        *(float4*)((float*)Wl + idx * 4) = *(const float4*)(Wemb + idx * 4);
    }
    #pragma unroll
    for (int it = 0; it < 8; it++) {
        int idx = it * 256 + t;
        int row = idx >> 5, c4 = idx & 31;
        float4 v = make_float4(0.f, 0.f, 0.f, 0.f);
        if (node0 + row < N_NODES) v = *(const float4*)(x + (size_t)(node0 + row) * F_IN + c4 * 4);
        *(float4*)&xs[row][c4 * 4] = v;
    }
    __syncthreads();
    int c = t & 7, g = t >> 3;
    float acc[2][4] = {};
    for (int k = 0; k < F_IN; k++) {
        float4 w4 = *(const float4*)&Wl[k][c * 4];
        #pragma unroll
        for (int n = 0; n < 2; n++) {
            float xv = xs[g * 2 + n][k];
            acc[n][0] += xv * w4.x; acc[n][1] += xv * w4.y;
            acc[n][2] += xv * w4.z; acc[n][3] += xv * w4.w;
        }
    }
    #pragma unroll
    for (int n = 0; n < 2; n++) {
        int node = node0 + g * 2 + n;
        if (node < N_NODES) {
            float4 o = make_float4(acc[n][0] + bl[c * 4], acc[n][1] + bl[c * 4 + 1],
                                   acc[n][2] + bl[c * 4 + 2], acc[n][3] + bl[c * 4 + 3]);
            *(float4*)(h0 + (size_t)node * HID + c * 4) = o;
        }
    }
}

// ================================================================ h1 = h0 @ W1 (bf16 out) + fused alpha1 dots
__global__ __launch_bounds__(256) void k_h1f(const float* __restrict__ h0,
                                             const float* __restrict__ W1,
                                             const float* __restrict__ a_src,
                                             const float* __restrict__ a_dst,
                                             unsigned short* __restrict__ h1,
                                             float* __restrict__ as, float* __restrict__ ad) {
    __shared__ float xs[64][36];
    __shared__ float Wl[HID][128];
    int t = threadIdx.x;
    int node0 = blockIdx.x * 64;
    #pragma unroll
    for (int it = 0; it < 4; it++) {
        int idx = it * 256 + t;
        *(float4*)((float*)Wl + idx * 4) = *(const float4*)(W1 + idx * 4);
    }
    #pragma unroll
    for (int it = 0; it < 2; it++) {
        int idx = it * 256 + t;
        int row = idx >> 3, c4 = idx & 7;
        float4 v = make_float4(0.f, 0.f, 0.f, 0.f);
        if (node0 + row < N_NODES) v = *(const float4*)(h0 + (size_t)(node0 + row) * HID + c4 * 4);
        *(float4*)&xs[row][c4 * 4] = v;
    }
    __syncthreads();
    int c = t & 31, g = t >> 5;
    float acc[8][4] = {};
    for (int k = 0; k < HID; k++) {
        float4 w4 = *(const float4*)&Wl[k][c * 4];
        #pragma unroll
        for (int n = 0; n < 8; n++) {
            float xv = xs[g * 8 + n][k];
            acc[n][0] += xv * w4.x; acc[n][1] += xv * w4.y;
            acc[n][2] += xv * w4.z; acc[n][3] += xv * w4.w;
        }
    }
    float4 av = *(const float4*)(a_src + c * 4);
    float4 dv = *(const float4*)(a_dst + c * 4);
    float ps[8], pd[8];
    #pragma unroll
    for (int n = 0; n < 8; n++) {
        int node = node0 + g * 8 + n;
        if (node < N_NODES) {
            ushort4 o;
            o.x = f2bf(acc[n][0]); o.y = f2bf(acc[n][1]);
            o.z = f2bf(acc[n][2]); o.w = f2bf(acc[n][3]);
            *(ushort4*)(h1 + (size_t)node * 128 + c * 4) = o;
        }
        ps[n] = acc[n][0] * av.x + acc[n][1] * av.y + acc[n][2] * av.z + acc[n][3] * av.w;
        pd[n] = acc[n][0] * dv.x + acc[n][1] * dv.y + acc[n][2] * dv.z + acc[n][3] * dv.w;
    }
    #pragma unroll
    for (int mask = 1; mask <= 4; mask <<= 1) {
        #pragma unroll
        for (int n = 0; n < 8; n++) {
            ps[n] += __shfl_xor(ps[n], mask, 64);
            pd[n] += __shfl_xor(pd[n], mask, 64);
        }
    }
    if ((c & 7) == 0) {
        int hh = c >> 3;
        #pragma unroll
        for (int n = 0; n < 8; n++) {
            int node = node0 + g * 8 + n;
            if (node < N_NODES) { as[node * 4 + hh] = ps[n]; ad[node * 4 + hh] = pd[n]; }
        }
    }
}

// ================================================================ h2 = out1 @ W2 (bf16 out) + fused alpha2 dots
__global__ __launch_bounds__(256) void k_h2f(const float* __restrict__ hin,
                                             const float* __restrict__ W2,
                                             const float* __restrict__ a_src,
                                             const float* __restrict__ a_dst,
                                             unsigned short* __restrict__ h2,
                                             float* __restrict__ as, float* __restrict__ ad) {
    __shared__ float xs[64][132];
    __shared__ float Wl[128][64];
    int t = threadIdx.x;
    int node0 = blockIdx.x * 64;
    #pragma unroll
    for (int it = 0; it < 8; it++) {
        int idx = it * 256 + t;
        *(float4*)((float*)Wl + idx * 4) = *(const float4*)(W2 + idx * 4);
    }
    #pragma unroll
    for (int it = 0; it < 8; it++) {
        int idx = it * 256 + t;
        int row = idx >> 5, c4 = idx & 31;
        float4 v = make_float4(0.f, 0.f, 0.f, 0.f);
        if (node0 + row < N_NODES) v = *(const float4*)(hin + (size_t)(node0 + row) * 128 + c4 * 4);
        *(float4*)&xs[row][c4 * 4] = v;
    }
    __syncthreads();
    int c = t & 15, g = t >> 4;
    float acc[4][4] = {};
    for (int k = 0; k < 128; k++) {
        float4 w4 = *(const float4*)&Wl[k][c * 4];
        #pragma unroll
        for (int n = 0; n < 4; n++) {
            float xv = xs[g * 4 + n][k];
            acc[n][0] += xv * w4.x; acc[n][1] += xv * w4.y;
            acc[n][2] += xv * w4.z; acc[n][3] += xv * w4.w;
        }
    }
    float4 av = *(const float4*)(a_src + c * 4);
    float4 dv = *(const float4*)(a_dst + c * 4);
    float ps[4], pd[4];
    #pragma unroll
    for (int n = 0; n < 4; n++) {
        int node = node0 + g * 4 + n;
        if (node < N_NODES) {
            ushort4 o;
            o.x = f2bf(acc[n][0]); o.y = f2bf(acc[n][1]);
            o.z = f2bf(acc[n][2]); o.w = f2bf(acc[n][3]);
            *(ushort4*)(h2 + (size_t)node * 64 + c * 4) = o;
        }
        ps[n] = acc[n][0] * av.x + acc[n][1] * av.y + acc[n][2] * av.z + acc[n][3] * av.w;
        pd[n] = acc[n][0] * dv.x + acc[n][1] * dv.y + acc[n][2] * dv.z + acc[n][3] * dv.w;
    }
    #pragma unroll
    for (int mask = 1; mask <= 2; mask <<= 1) {
        #pragma unroll
        for (int n = 0; n < 4; n++) {
            ps[n] += __shfl_xor(ps[n], mask, 64);
            pd[n] += __shfl_xor(pd[n], mask, 64);
        }
    }
    if ((c & 3) == 0) {
        int hh = c >> 2;
        #pragma unroll
        for (int n = 0; n < 4; n++) {
            int node = node0 + g * 4 + n;
            if (node < N_NODES) { as[node * 4 + hh] = ps[n]; ad[node * 4 + hh] = pd[n]; }
        }
    }
}

__device__ __forceinline__ float edge_w(float asv, float adv) {
    float v = asv + adv;
    v = (v > 0.f) ? v : 0.2f * v;        // leaky_relu(0.2)
    return __expf(v);                    // softmax shift-invariant; logits O(1)
}

// ================================================================ layer-1 gather (bf16 table, shuffle-shared w)
__global__ __launch_bounds__(256) void k_gather1(const int* __restrict__ esrc,
                                                 const int* __restrict__ rowptr,
                                                 const unsigned int* __restrict__ h1,   // bf16x2 words
                                                 const float* __restrict__ as,
                                                 const float* __restrict__ ad,
                                                 const float* __restrict__ b1,
                                                 float* __restrict__ out1) {
    int t = threadIdx.x;
    int node = blockIdx.x * 4 + (t >> 6);
    int lane = t & 63;
    int head = lane >> 4;
    int i4 = (lane >> 2) & 3;
    int h4 = lane & 3;
    int beg = rowptr[node], end = rowptr[node + 1];
    float ad_w = ad[node * 4 + h4];
    float adn = __shfl(ad_w, head, 64);
    float ax = 0.f, ay = 0.f, s = 0.f;
    int k = beg;
    for (; k + 4 <= end; k += 4) {
        int s0 = esrc[k], s1 = esrc[k + 1], s2 = esrc[k + 2], s3 = esrc[k + 3];
        int sm = (i4 < 2) ? (i4 == 0 ? s0 : s1) : (i4 == 2 ? s2 : s3);
        float wm = edge_w(as[sm * 4 + h4], ad_w);
        float w0 = __shfl(wm, head, 64);
        float w1 = __shfl(wm, 4 | head, 64);
        float w2 = __shfl(wm, 8 | head, 64);
        float w3 = __shfl(wm, 12 | head, 64);
        unsigned int u0 = h1[(size_t)s0 * 64 + lane];
        unsigned int u1 = h1[(size_t)s1 * 64 + lane];
        unsigned int u2 = h1[(size_t)s2 * 64 + lane];
        unsigned int u3 = h1[(size_t)s3 * 64 + lane];
        ax += __uint_as_float(u0 << 16) * w0 + __uint_as_float(u1 << 16) * w1
            + __uint_as_float(u2 << 16) * w2 + __uint_as_float(u3 << 16) * w3;
        ay += __uint_as_float(u0 & 0xFFFF0000u) * w0 + __uint_as_float(u1 & 0xFFFF0000u) * w1
            + __uint_as_float(u2 & 0xFFFF0000u) * w2 + __uint_as_float(u3 & 0xFFFF0000u) * w3;
        s += w0 + w1 + w2 + w3;
    }
    for (; k < end; k++) {
        int sv = esrc[k];
        float w = edge_w(as[sv * 4 + head], adn);
        unsigned int u = h1[(size_t)sv * 64 + lane];
        ax += __uint_as_float(u << 16) * w;
        ay += __uint_as_float(u & 0xFFFF0000u) * w;
        s += w;
    }
    float rs = 1.0f / (s + 1e-16f);
    float2 bv = *(const float2*)(b1 + 2 * lane);
    float vx = ax * rs + bv.x;
    float vy = ay * rs + bv.y;
    vx = (vx > 0.f) ? vx : (__expf(vx) - 1.0f);   // ELU
    vy = (vy > 0.f) ? vy : (__expf(vy) - 1.0f);
    *(float2*)(out1 + (size_t)node * 128 + 2 * lane) = make_float2(vx, vy);
}

// ================================================================ layer-2 gather + head-mean + b2 + log_softmax
__global__ __launch_bounds__(256) void k_gather2(const int* __restrict__ esrc,
                                                 const int* __restrict__ rowptr,
                                                 const unsigned short* __restrict__ h2,
                                                 const float* __restrict__ as,
                                                 const float* __restrict__ ad,
                                                 const float* __restrict__ b2,
                                                 float* __restrict__ out) {
    int t = threadIdx.x;
    int node = blockIdx.x * 4 + (t >> 6);
    int lane = t & 63;
    int head = lane >> 4, c = lane & 15;
    int i4 = (lane >> 2) & 3;
    int h4 = lane & 3;
    int beg = rowptr[node], end = rowptr[node + 1];
    float ad_w = ad[node * 4 + h4];
    float adn = __shfl(ad_w, head, 64);
    float acc = 0.f, s = 0.f;
    int k = beg;
    for (; k + 4 <= end; k += 4) {
        int s0 = esrc[k], s1 = esrc[k + 1], s2 = esrc[k + 2], s3 = esrc[k + 3];
        int sm = (i4 < 2) ? (i4 == 0 ? s0 : s1) : (i4 == 2 ? s2 : s3);
        float wm = edge_w(as[sm * 4 + h4], ad_w);
        float w0 = __shfl(wm, head, 64);
        float w1 = __shfl(wm, 4 | head, 64);
        float w2 = __shfl(wm, 8 | head, 64);
        float w3 = __shfl(wm, 12 | head, 64);
        float r0 = bf2f(h2[(size_t)s0 * 64 + lane]);
        float r1 = bf2f(h2[(size_t)s1 * 64 + lane]);
        float r2 = bf2f(h2[(size_t)s2 * 64 + lane]);
        float r3 = bf2f(h2[(size_t)s3 * 64 + lane]);
        acc += r0 * w0 + r1 * w1 + r2 * w2 + r3 * w3;
        s += w0 + w1 + w2 + w3;
    }
    for (; k < end; k++) {
        int sv = esrc[k];
        float w = edge_w(as[sv * 4 + head], adn);
        acc += bf2f(h2[(size_t)sv * 64 + lane]) * w;
        s += w;
    }
    float v = acc * (1.0f / (s + 1e-16f));
    v += __shfl_xor(v, 16, 64);
    v += __shfl_xor(v, 32, 64);
    v = v * 0.25f + b2[c];
    float m = v;
    #pragma unroll
    for (int mask = 1; mask < 16; mask <<= 1) m = fmaxf(m, __shfl_xor(m, mask, 64));
    float ex = __expf(v - m);
    float se = ex;
    #pragma unroll
    for (int mask = 1; mask < 16; mask <<= 1) se += __shfl_xor(se, mask, 64);
    float res = (v - m) - __logf(se);
    if (lane < 16) out[(size_t)node * 16 + lane] = res;
}

// ================================================================ host
extern "C" void kernel_launch(void* const* d_in, const int* in_sizes, int n_in,
                              void* d_out, int out_size, void* d_ws, size_t ws_size,
                              hipStream_t stream) {
    const float* x      = (const float*)d_in[0];
    const int*   ei     = (const int*)d_in[1];
    const float* Wemb   = (const float*)d_in[2];
    const float* bemb   = (const float*)d_in[3];
    const float* W1     = (const float*)d_in[4];
    const float* a_src1 = (const float*)d_in[5];
    const float* a_dst1 = (const float*)d_in[6];
    const float* b1     = (const float*)d_in[7];
    const float* W2     = (const float*)d_in[8];
    const float* a_src2 = (const float*)d_in[9];
    const float* a_dst2 = (const float*)d_in[10];
    const float* b2     = (const float*)d_in[11];
    float* out = (float*)d_out;

    char* ws = (char*)d_ws;
    size_t off = 0;
    auto alloc = [&](size_t bytes) { char* p = ws + off; off += (bytes + 255) & ~size_t(255); return p; };
    float*          out1 = (float*)alloc((size_t)N_NODES * 128 * 4);            // h0 [N,32] overlays front
    unsigned short* h1b  = (unsigned short*)alloc((size_t)N_NODES * 128 * 2);   // h2b [N,64] overlays front
    int*          esrc   = (int*)alloc((size_t)N_EDGES * 4);
    unsigned int* pairs  = (unsigned int*)alloc((size_t)NBKT * CAP * 4);        // 4.0 MB
    float* as     = (float*)alloc((size_t)N_NODES * 4 * 4);
    float* ad     = (float*)alloc((size_t)N_NODES * 4 * 4);
    int*   rowptr = (int*)alloc((size_t)(N_NODES + 1) * 4);
    int*   gcnt   = (int*)alloc((size_t)NBKT * 4);
    int*   bbase  = (int*)alloc((size_t)NBKT * 4);
    float*          h0  = out1;    // dead before gather1 writes out1
    unsigned short* h2b = h1b;     // h1b dead after gather1

    const int NB64 = (N_NODES + 63) / 64;   // 782
    const int GB   = N_NODES / 4;           // 12500
    const int AB   = (N_EDGES + EPB - 1) / EPB;  // 196

    // --- CSR (dst-sorted src list), bucketed 2-phase counting sort
    hipMemsetAsync(gcnt, 0, (size_t)NBKT * 4, stream);
    k_bucketA<<<AB, 256, 0, stream>>>(ei, gcnt, pairs);
    k_bucketS<<<1, 256, 0, stream>>>(gcnt, bbase);
    k_bucketB<<<NBKT, 256, 0, stream>>>(pairs, gcnt, bbase, rowptr, esrc);

    // --- features + layer 1
    k_emb<<<NB64, 256, 0, stream>>>(x, Wemb, bemb, h0);
    k_h1f<<<NB64, 256, 0, stream>>>(h0, W1, a_src1, a_dst1, h1b, as, ad);
    k_gather1<<<GB, 256, 0, stream>>>(esrc, rowptr, (const unsigned int*)h1b, as, ad, b1, out1);

    // --- layer 2 (softmax+aggregate+mean+log_softmax fused in gather2)
    k_h2f<<<NB64, 256, 0, stream>>>(out1, W2, a_src2, a_dst2, h2b, as, ad);
    k_gather2<<<GB, 256, 0, stream>>>(esrc, rowptr, h2b, as, ad, b2, out);
}